// Round 2
// baseline (1285.485 us; speedup 1.0000x reference)
//
#include <hip/hip_runtime.h>

#define F 64
#define N_NODES 8192
#define E_EDGES 262144
#define EF 32
#define HID 64
#define MLP_IN (2*F + EF + 1)   // 161
#define INV_AVG (1.0f/32.0f)
#define INV_SQRT3 0.57735026918962576f
#define INV_SQRT2 0.70710678118654752f

__device__ __forceinline__ float silu(float x) {
    return x / (1.0f + __expf(-x));
}

// ---------------------------------------------------------------------------
// Kernel 1: node transforms.
//   NS  = s @ Wsc   (N,64)   SUP = s @ Wup_s (N,64)   VUP[n][c][g] (N,3,64)
// ---------------------------------------------------------------------------
__global__ __launch_bounds__(64) void node_kernel(
    const float* __restrict__ node_feats,
    const float* __restrict__ Wsc,
    const float* __restrict__ Wup_s,
    const float* __restrict__ Wup_v,
    float* __restrict__ NS,
    float* __restrict__ SUP,
    float* __restrict__ VUP) {
    const int n = blockIdx.x;
    const int g = threadIdx.x;
    __shared__ float s_lds[64];
    __shared__ float v_lds[3][64];

    const float* nf = node_feats + (size_t)n * 256;
    s_lds[g] = nf[g];
    v_lds[0][g] = nf[64 + g * 3 + 0];
    v_lds[1][g] = nf[64 + g * 3 + 1];
    v_lds[2][g] = nf[64 + g * 3 + 2];
    __syncthreads();

    float ns = 0.f, su = 0.f, vu0 = 0.f, vu1 = 0.f, vu2 = 0.f;
#pragma unroll 8
    for (int k = 0; k < 64; ++k) {
        const float sk = s_lds[k];
        ns += sk * Wsc[k * 64 + g];
        su += sk * Wup_s[k * 64 + g];
        const float w = Wup_v[k * 64 + g];
        vu0 += v_lds[0][k] * w;
        vu1 += v_lds[1][k] * w;
        vu2 += v_lds[2][k] * w;
    }
    NS[n * 64 + g] = ns;
    SUP[n * 64 + g] = su;
    VUP[(n * 3 + 0) * 64 + g] = vu0;
    VUP[(n * 3 + 1) * 64 + g] = vu1;
    VUP[(n * 3 + 2) * 64 + g] = vu2;
}

// ---------------------------------------------------------------------------
// Kernel 2: fused edge kernel, lane = edge arrangement.
// Block = 2 waves; each wave owns 64 consecutive edges. Lane j holds edge
// e0+j. MLP accumulators live in VGPRs (acc[64], g unrolled); weights are
// wave-uniform -> scalar loads; activations stream from conflict-free LDS.
// Layer-3 output chunks are transposed through LDS back to lane=feature for
// the tensor product + coalesced atomic scatter.
// ---------------------------------------------------------------------------
#define WPB 2
__global__ __launch_bounds__(128) void edge_kernel(
    const float* __restrict__ edge_attrs,
    const float* __restrict__ edge_feats,
    const float* __restrict__ lengths,
    const int*   __restrict__ edge_index,
    const float* __restrict__ W1, const float* __restrict__ b1,
    const float* __restrict__ W2, const float* __restrict__ b2,
    const float* __restrict__ W3,
    const float* __restrict__ NS,
    const float* __restrict__ SUP,
    const float* __restrict__ VUP,
    float* __restrict__ M0,
    float* __restrict__ M1) {
    const int w    = threadIdx.x >> 6;
    const int lane = threadIdx.x & 63;
    const int e0   = (blockIdx.x * WPB + w) * 64;   // wave's first edge
    const int e    = e0 + lane;                     // this lane's edge

    // LDS: per-wave regions, conflict-free layouts.
    __shared__ float h12t[WPB][64][64];   // [k][j] column(edge)-major, 16KB/wave
    __shared__ float xt[WPB][64][33];     // [j][kk] odd stride, 8.45KB/wave
    __shared__ int   snd_s[WPB][64];
    __shared__ int   rcv_s[WPB][64];
    __shared__ float len_s[WPB][64];
    __shared__ float attr_s[WPB][4][64];

    // ---- stage edge metadata ----
    snd_s[w][lane] = edge_index[e];
    rcv_s[w][lane] = edge_index[E_EDGES + e];
    len_s[w][lane] = lengths[e];
    const float4 a4 = ((const float4*)edge_attrs)[e];
    attr_s[w][0][lane] = a4.x;
    attr_s[w][1][lane] = a4.y;
    attr_s[w][2][lane] = a4.z;
    attr_s[w][3][lane] = a4.w;
    __syncthreads();

    // ---- layer 1: 161 -> 64 ----
    float acc[64];
#pragma unroll
    for (int g = 0; g < 64; ++g) acc[g] = b1[g];

    for (int t = 0; t < 5; ++t) {           // 5 k-tiles of 32
        // stage tile: 64 edges x 32 features, 2 edges per instruction
        for (int i = 0; i < 32; ++i) {
            const int j  = 2 * i + (lane >> 5);
            const int kk = lane & 31;
            float v;
            if (t < 4) {
                const int node = (t < 2) ? snd_s[w][j] : rcv_s[w][j];
                v = NS[node * 64 + (t & 1) * 32 + kk];
            } else {
                v = edge_feats[(size_t)(e0 + j) * EF + kk];
            }
            xt[w][j][kk] = v;
        }
        __syncthreads();
        for (int kk = 0; kk < 32; ++kk) {
            const float x = xt[w][lane][kk];
            const float* wr = W1 + (t * 32 + kk) * 64;
#pragma unroll
            for (int g = 0; g < 64; ++g) acc[g] += x * wr[g];
        }
        __syncthreads();
    }
    {   // k = 160: length
        const float x = len_s[w][lane];
        const float* wr = W1 + 160 * 64;
#pragma unroll
        for (int g = 0; g < 64; ++g) acc[g] += x * wr[g];
    }
    // silu -> h1 in LDS ([k][j] layout)
#pragma unroll
    for (int g = 0; g < 64; ++g) h12t[w][g][lane] = silu(acc[g]);
    __syncthreads();

    // ---- layer 2: 64 -> 64 ----
    float acc2[64];
#pragma unroll
    for (int g = 0; g < 64; ++g) acc2[g] = b2[g];
    for (int k = 0; k < 64; ++k) {
        const float x = h12t[w][k][lane];
        const float* wr = W2 + k * 64;
#pragma unroll
        for (int g = 0; g < 64; ++g) acc2[g] += x * wr[g];
    }
    __syncthreads();
#pragma unroll
    for (int g = 0; g < 64; ++g) h12t[w][g][lane] = silu(acc2[g]);
    __syncthreads();

    // ---- layer 3 (5 chunks of 64) + tensor product + scatter ----
    const int halfsel = lane >> 5;
    const int gl      = lane & 31;

    for (int c = 0; c < 5; ++c) {
        float acc3[64];
#pragma unroll
        for (int g = 0; g < 64; ++g) acc3[g] = 0.f;
        for (int k = 0; k < 64; ++k) {
            const float x = h12t[w][k][lane];
            const float* wr = W3 + k * 320 + c * 64;
#pragma unroll
            for (int g = 0; g < 64; ++g) acc3[g] += x * wr[g];
        }

        // transpose + consume in two 32-feature halves
#pragma unroll
        for (int hh = 0; hh < 2; ++hh) {
#pragma unroll
            for (int gp = 0; gp < 32; ++gp) xt[w][lane][gp] = acc3[hh * 32 + gp];
            __syncthreads();

            const int g = hh * 32 + gl;     // feature this lane handles
            for (int jp = 0; jp < 32; ++jp) {
                const int j = 2 * jp + halfsel;       // edge within wave
                const float tv   = xt[w][j][gl];
                const int   sndj = snd_s[w][j];
                const int   rcvj = rcv_s[w][j];

                if (c == 0) {
                    const float ss  = SUP[sndj * 64 + g];
                    const float a0j = attr_s[w][0][j];
                    atomicAdd(&M0[(size_t)rcvj * 128 + g], ss * a0j * tv);
                } else if (c == 1) {
                    const float v0 = VUP[(sndj * 3 + 0) * 64 + g];
                    const float v1 = VUP[(sndj * 3 + 1) * 64 + g];
                    const float v2 = VUP[(sndj * 3 + 2) * 64 + g];
                    const float p  = (v0 * attr_s[w][1][j] + v1 * attr_s[w][2][j]
                                      + v2 * attr_s[w][3][j]) * INV_SQRT3;
                    atomicAdd(&M0[(size_t)rcvj * 128 + 64 + g], p * tv);
                } else if (c == 2) {
                    const float ss = SUP[sndj * 64 + g];
                    float* M1r = M1 + (size_t)rcvj * 576;
                    atomicAdd(M1r + 0 * 192 + g, ss * attr_s[w][1][j] * tv);
                    atomicAdd(M1r + 1 * 192 + g, ss * attr_s[w][2][j] * tv);
                    atomicAdd(M1r + 2 * 192 + g, ss * attr_s[w][3][j] * tv);
                } else if (c == 3) {
                    const float a0j = attr_s[w][0][j];
                    const float v0 = VUP[(sndj * 3 + 0) * 64 + g];
                    const float v1 = VUP[(sndj * 3 + 1) * 64 + g];
                    const float v2 = VUP[(sndj * 3 + 2) * 64 + g];
                    float* M1r = M1 + (size_t)rcvj * 576;
                    atomicAdd(M1r + 0 * 192 + 64 + g, v0 * a0j * tv);
                    atomicAdd(M1r + 1 * 192 + 64 + g, v1 * a0j * tv);
                    atomicAdd(M1r + 2 * 192 + 64 + g, v2 * a0j * tv);
                } else {
                    const float a10 = attr_s[w][1][j];
                    const float a11 = attr_s[w][2][j];
                    const float a12 = attr_s[w][3][j];
                    const float v0 = VUP[(sndj * 3 + 0) * 64 + g];
                    const float v1 = VUP[(sndj * 3 + 1) * 64 + g];
                    const float v2 = VUP[(sndj * 3 + 2) * 64 + g];
                    const float s2t = INV_SQRT2 * tv;
                    float* M1r = M1 + (size_t)rcvj * 576;
                    atomicAdd(M1r + 0 * 192 + 128 + g, (v1 * a12 - v2 * a11) * s2t);
                    atomicAdd(M1r + 1 * 192 + 128 + g, (v2 * a10 - v0 * a12) * s2t);
                    atomicAdd(M1r + 2 * 192 + 128 + g, (v0 * a11 - v1 * a10) * s2t);
                }
            }
            __syncthreads();
        }
    }
}

// ---------------------------------------------------------------------------
// Kernel 3: per-node output projections.
// ---------------------------------------------------------------------------
__global__ __launch_bounds__(256) void out_kernel(
    const float* __restrict__ M0,
    const float* __restrict__ M1,
    const float* __restrict__ Wl0,
    const float* __restrict__ Wl1,
    float* __restrict__ out) {
    const int n = blockIdx.x;
    const int t = threadIdx.x;
    __shared__ float m0[128];
    __shared__ float m1[3][192];
    __shared__ float o_lds[256];

    if (t < 128) m0[t] = M0[(size_t)n * 128 + t];
    for (int i = t; i < 576; i += 256) m1[i / 192][i % 192] = M1[(size_t)n * 576 + i];
    __syncthreads();

    const int c = t >> 6;
    const int g = t & 63;
    float acc = 0.f;
    if (c == 0) {
#pragma unroll 8
        for (int k = 0; k < 128; ++k) acc += m0[k] * Wl0[k * 64 + g];
    } else {
        const float* m = m1[c - 1];
#pragma unroll 8
        for (int k = 0; k < 192; ++k) acc += m[k] * Wl1[k * 64 + g];
    }
    o_lds[g * 4 + c] = acc * INV_AVG;
    __syncthreads();
    out[(size_t)n * 256 + t] = o_lds[t];
}

extern "C" void kernel_launch(void* const* d_in, const int* in_sizes, int n_in,
                              void* d_out, int out_size, void* d_ws, size_t ws_size,
                              hipStream_t stream) {
    const float* node_feats = (const float*)d_in[0];
    const float* edge_attrs = (const float*)d_in[1];
    const float* edge_feats = (const float*)d_in[2];
    const float* lengths    = (const float*)d_in[3];
    const int*   edge_index = (const int*)d_in[4];
    const float* Wsc   = (const float*)d_in[5];
    const float* Wup_s = (const float*)d_in[6];
    const float* Wup_v = (const float*)d_in[7];
    const float* W1 = (const float*)d_in[8];
    const float* b1 = (const float*)d_in[9];
    const float* W2 = (const float*)d_in[10];
    const float* b2 = (const float*)d_in[11];
    const float* W3 = (const float*)d_in[12];
    const float* Wl0 = (const float*)d_in[13];
    const float* Wl1 = (const float*)d_in[14];

    float* ws  = (float*)d_ws;
    float* NS  = ws;                            // N*64
    float* SUP = NS  + (size_t)N_NODES * 64;    // N*64
    float* VUP = SUP + (size_t)N_NODES * 64;    // N*192
    float* M0  = VUP + (size_t)N_NODES * 192;   // N*128
    float* M1  = M0  + (size_t)N_NODES * 128;   // N*576

    hipMemsetAsync(M0, 0, (size_t)N_NODES * (128 + 576) * sizeof(float), stream);

    node_kernel<<<N_NODES, 64, 0, stream>>>(node_feats, Wsc, Wup_s, Wup_v, NS, SUP, VUP);
    edge_kernel<<<E_EDGES / (64 * WPB), 64 * WPB, 0, stream>>>(
        edge_attrs, edge_feats, lengths, edge_index,
        W1, b1, W2, b2, W3, NS, SUP, VUP, M0, M1);
    out_kernel<<<N_NODES, 256, 0, stream>>>(M0, M1, Wl0, Wl1, (float*)d_out);
}

// Round 4
// 1205.587 us; speedup vs baseline: 1.0663x; 1.0663x over previous
//
#include <hip/hip_runtime.h>

#define F 64
#define N_NODES 8192
#define E_EDGES 262144
#define EF 32
#define HID 64
#define INV_AVG (1.0f/32.0f)
#define INV_SQRT3 0.57735026918962576f
#define INV_SQRT2 0.70710678118654752f

__device__ __forceinline__ float silu(float x) {
    return x / (1.0f + __expf(-x));
}

// ---------------------------------------------------------------------------
// Sort prologue: counting sort of edges by rcv.
// ---------------------------------------------------------------------------
__global__ __launch_bounds__(256) void hist_kernel(
    const int* __restrict__ edge_index, int* __restrict__ cnt) {
    const int e = blockIdx.x * 256 + threadIdx.x;
    atomicAdd(&cnt[edge_index[E_EDGES + e]], 1);
}

// Single block: exclusive scan of 8192 counts -> offs.
__global__ __launch_bounds__(256) void scan_kernel(
    const int* __restrict__ cnt, int* __restrict__ offs) {
    __shared__ int part[256];
    const int t = threadIdx.x;
    int local[32];
    int s = 0;
#pragma unroll
    for (int i = 0; i < 32; ++i) { local[i] = s; s += cnt[t * 32 + i]; }
    part[t] = s;
    __syncthreads();
    for (int d = 1; d < 256; d <<= 1) {
        int v = (t >= d) ? part[t - d] : 0;
        __syncthreads();
        part[t] += v;
        __syncthreads();
    }
    const int prefix = (t == 0) ? 0 : part[t - 1];
#pragma unroll
    for (int i = 0; i < 32; ++i) offs[t * 32 + i] = prefix + local[i];
}

__global__ __launch_bounds__(256) void perm_kernel(
    const int* __restrict__ edge_index, int* __restrict__ offs,
    int* __restrict__ perm) {
    const int e = blockIdx.x * 256 + threadIdx.x;
    const int pos = atomicAdd(&offs[edge_index[E_EDGES + e]], 1);
    perm[pos] = e;
}

// ---------------------------------------------------------------------------
// Kernel: node transforms.  NS = s@Wsc, SUP = s@Wup_s, VUP[n][c][g] = v@Wup_v
// ---------------------------------------------------------------------------
__global__ __launch_bounds__(64) void node_kernel(
    const float* __restrict__ node_feats,
    const float* __restrict__ Wsc,
    const float* __restrict__ Wup_s,
    const float* __restrict__ Wup_v,
    float* __restrict__ NS,
    float* __restrict__ SUP,
    float* __restrict__ VUP) {
    const int n = blockIdx.x;
    const int g = threadIdx.x;
    __shared__ float s_lds[64];
    __shared__ float v_lds[3][64];

    const float* nf = node_feats + (size_t)n * 256;
    s_lds[g] = nf[g];
    v_lds[0][g] = nf[64 + g * 3 + 0];
    v_lds[1][g] = nf[64 + g * 3 + 1];
    v_lds[2][g] = nf[64 + g * 3 + 2];
    __syncthreads();

    float ns = 0.f, su = 0.f, vu0 = 0.f, vu1 = 0.f, vu2 = 0.f;
#pragma unroll 8
    for (int k = 0; k < 64; ++k) {
        const float sk = s_lds[k];
        ns += sk * Wsc[k * 64 + g];
        su += sk * Wup_s[k * 64 + g];
        const float w = Wup_v[k * 64 + g];
        vu0 += v_lds[0][k] * w;
        vu1 += v_lds[1][k] * w;
        vu2 += v_lds[2][k] * w;
    }
    NS[n * 64 + g] = ns;
    SUP[n * 64 + g] = su;
    VUP[(n * 3 + 0) * 64 + g] = vu0;
    VUP[(n * 3 + 1) * 64 + g] = vu1;
    VUP[(n * 3 + 2) * 64 + g] = vu2;
}

// ---------------------------------------------------------------------------
// Fused edge kernel, lane = edge, edges processed in rcv-sorted order.
// MLP state entirely in registers (static indices via full unroll on the
// k-loops; outer chunk loops stay ROLLED so code stays ~30KB and fits I$).
// Weights are wave-uniform -> scalar loads. LDS: 64x33 transpose buffer +
// edge metadata per wave. Explicit barriers at every cross-lane hand-off.
// Scatter: lane=feature via LDS transpose, run-aggregated over sorted rcv,
// atomic flush only at run boundaries.
// ---------------------------------------------------------------------------
#define WPB 2
__global__ __launch_bounds__(128) void edge_kernel(
    const float* __restrict__ edge_attrs,
    const float* __restrict__ edge_feats,
    const float* __restrict__ lengths,
    const int*   __restrict__ edge_index,
    const int*   __restrict__ perm,
    const float* __restrict__ W1, const float* __restrict__ b1,
    const float* __restrict__ W2, const float* __restrict__ b2,
    const float* __restrict__ W3,
    const float* __restrict__ NS,
    const float* __restrict__ SUP,
    const float* __restrict__ VUP,
    float* __restrict__ M0,
    float* __restrict__ M1) {
    const int w    = threadIdx.x >> 6;
    const int lane = threadIdx.x & 63;
    const int e0   = (blockIdx.x * WPB + w) * 64;

    __shared__ float xt[WPB][64][33];     // staging / transpose / h2-stash
    __shared__ int   snd_s[WPB][64];
    __shared__ int   rcv_s[WPB][64];
    __shared__ int   pe_s[WPB][64];
    __shared__ float attr_s[WPB][4][64];

    // ---- edge metadata (sorted order) ----
    const int pe  = perm[e0 + lane];
    const int snd = edge_index[pe];
    const int rcv = edge_index[E_EDGES + pe];
    const float len = lengths[pe];
    const float4 a4 = ((const float4*)edge_attrs)[pe];
    snd_s[w][lane] = snd;
    rcv_s[w][lane] = rcv;
    pe_s[w][lane]  = pe;
    attr_s[w][0][lane] = a4.x;
    attr_s[w][1][lane] = a4.y;
    attr_s[w][2][lane] = a4.z;
    attr_s[w][3][lane] = a4.w;
    __syncthreads();

    // ---- layer 1: 161 -> 64, acc[g] in VGPRs ----
    float acc[64];
#pragma unroll
    for (int g = 0; g < 64; ++g) acc[g] = b1[g];

    for (int t = 0; t < 5; ++t) {
        // stage 64 edges x 32 features
        for (int i = 0; i < 32; ++i) {
            const int j  = 2 * i + (lane >> 5);
            const int kk = lane & 31;
            float v;
            if (t < 4) {
                const int node = (t < 2) ? snd_s[w][j] : rcv_s[w][j];
                v = NS[node * 64 + (t & 1) * 32 + kk];
            } else {
                v = edge_feats[(size_t)pe_s[w][j] * EF + kk];
            }
            xt[w][j][kk] = v;
        }
        __syncthreads();
        for (int kk = 0; kk < 32; ++kk) {
            const float x = xt[w][lane][kk];
            const float* wr = W1 + (t * 32 + kk) * 64;
#pragma unroll
            for (int g = 0; g < 64; ++g) acc[g] += x * wr[g];
        }
        __syncthreads();
    }
    {   // k = 160: length (lane-local)
        const float* wr = W1 + 160 * 64;
#pragma unroll
        for (int g = 0; g < 64; ++g) acc[g] += len * wr[g];
    }
#pragma unroll
    for (int k = 0; k < 64; ++k) acc[k] = silu(acc[k]);   // h1 in regs

    // ---- layer 2: 64 -> 64 in two 32-chunks (VGPR cap) ----
    // ch=0: g in [32,64) -> stash silu to LDS (own row, lane-local);
    // ch=1: g in [0,32)  -> overwrite acc[0:32], then reload stash.
    for (int ch = 0; ch < 2; ++ch) {
        const int gbase = (ch == 0) ? 32 : 0;
        const float* W2b = W2 + gbase;
        float acc2[32];
#pragma unroll
        for (int gg = 0; gg < 32; ++gg) acc2[gg] = b2[gbase + gg];
#pragma unroll
        for (int k = 0; k < 64; ++k) {
            const float hk = acc[k];
#pragma unroll
            for (int gg = 0; gg < 32; ++gg) acc2[gg] += hk * W2b[k * 64 + gg];
        }
        if (ch == 0) {
#pragma unroll
            for (int gg = 0; gg < 32; ++gg) xt[w][lane][gg] = silu(acc2[gg]);
        } else {
#pragma unroll
            for (int gg = 0; gg < 32; ++gg) acc[gg] = silu(acc2[gg]);
#pragma unroll
            for (int gg = 0; gg < 32; ++gg) acc[32 + gg] = xt[w][lane][gg];
        }
    }
    // acc[] now holds h2.

    // ---- layer 3 (ten 32-wide chunks) + transpose + run-aggregated scatter
    const int halfsel = lane >> 5;
    const int gl      = lane & 31;

    for (int c = 0; c < 5; ++c) {
        for (int hh = 0; hh < 2; ++hh) {
            const float* W3b = W3 + c * 64 + hh * 32;
            float acc3[32];
#pragma unroll
            for (int gg = 0; gg < 32; ++gg) acc3[gg] = 0.f;
#pragma unroll
            for (int k = 0; k < 64; ++k) {
                const float hk = acc[k];
#pragma unroll
                for (int gg = 0; gg < 32; ++gg) acc3[gg] += hk * W3b[k * 320 + gg];
            }
            // transpose to lane=feature (barrier: prev readers done first)
            __syncthreads();
#pragma unroll
            for (int gg = 0; gg < 32; ++gg) xt[w][lane][gg] = acc3[gg];
            __syncthreads();

            const int g = hh * 32 + gl;
            int   cur = -1;
            float r0 = 0.f, r1 = 0.f, r2 = 0.f;
            for (int jp = 0; jp < 32; ++jp) {
                const int j = 32 * halfsel + jp;   // contiguous sorted range
                const int rcvj = rcv_s[w][j];
                if (rcvj != cur) {
                    if (cur >= 0) {
                        if (c == 0)      atomicAdd(&M0[(size_t)cur * 128 + g], r0);
                        else if (c == 1) atomicAdd(&M0[(size_t)cur * 128 + 64 + g], r0);
                        else {
                            float* M1r = M1 + (size_t)cur * 576;
                            const int off = (c == 2) ? 0 : (c == 3) ? 64 : 128;
                            atomicAdd(M1r + off + g, r0);
                            atomicAdd(M1r + 192 + off + g, r1);
                            atomicAdd(M1r + 384 + off + g, r2);
                        }
                    }
                    cur = rcvj; r0 = r1 = r2 = 0.f;
                }
                const int   sndj = snd_s[w][j];
                const float tv   = xt[w][j][gl];
                if (c == 0) {
                    r0 += SUP[sndj * 64 + g] * attr_s[w][0][j] * tv;
                } else if (c == 1) {
                    const float v0 = VUP[(sndj * 3 + 0) * 64 + g];
                    const float v1 = VUP[(sndj * 3 + 1) * 64 + g];
                    const float v2 = VUP[(sndj * 3 + 2) * 64 + g];
                    r0 += (v0 * attr_s[w][1][j] + v1 * attr_s[w][2][j]
                           + v2 * attr_s[w][3][j]) * (INV_SQRT3 * tv);
                } else if (c == 2) {
                    const float sstv = SUP[sndj * 64 + g] * tv;
                    r0 += sstv * attr_s[w][1][j];
                    r1 += sstv * attr_s[w][2][j];
                    r2 += sstv * attr_s[w][3][j];
                } else if (c == 3) {
                    const float a0tv = attr_s[w][0][j] * tv;
                    r0 += VUP[(sndj * 3 + 0) * 64 + g] * a0tv;
                    r1 += VUP[(sndj * 3 + 1) * 64 + g] * a0tv;
                    r2 += VUP[(sndj * 3 + 2) * 64 + g] * a0tv;
                } else {
                    const float v0 = VUP[(sndj * 3 + 0) * 64 + g];
                    const float v1 = VUP[(sndj * 3 + 1) * 64 + g];
                    const float v2 = VUP[(sndj * 3 + 2) * 64 + g];
                    const float a1j = attr_s[w][1][j];
                    const float a2j = attr_s[w][2][j];
                    const float a3j = attr_s[w][3][j];
                    const float s2t = INV_SQRT2 * tv;
                    r0 += (v1 * a3j - v2 * a2j) * s2t;
                    r1 += (v2 * a1j - v0 * a3j) * s2t;
                    r2 += (v0 * a2j - v1 * a1j) * s2t;
                }
            }
            // final flush
            if (cur >= 0) {
                if (c == 0)      atomicAdd(&M0[(size_t)cur * 128 + g], r0);
                else if (c == 1) atomicAdd(&M0[(size_t)cur * 128 + 64 + g], r0);
                else {
                    float* M1r = M1 + (size_t)cur * 576;
                    const int off = (c == 2) ? 0 : (c == 3) ? 64 : 128;
                    atomicAdd(M1r + off + g, r0);
                    atomicAdd(M1r + 192 + off + g, r1);
                    atomicAdd(M1r + 384 + off + g, r2);
                }
            }
        }
    }
}

// ---------------------------------------------------------------------------
// Kernel: per-node output projections.
// ---------------------------------------------------------------------------
__global__ __launch_bounds__(256) void out_kernel(
    const float* __restrict__ M0,
    const float* __restrict__ M1,
    const float* __restrict__ Wl0,
    const float* __restrict__ Wl1,
    float* __restrict__ out) {
    const int n = blockIdx.x;
    const int t = threadIdx.x;
    __shared__ float m0[128];
    __shared__ float m1[3][192];
    __shared__ float o_lds[256];

    if (t < 128) m0[t] = M0[(size_t)n * 128 + t];
    for (int i = t; i < 576; i += 256) m1[i / 192][i % 192] = M1[(size_t)n * 576 + i];
    __syncthreads();

    const int c = t >> 6;
    const int g = t & 63;
    float acc = 0.f;
    if (c == 0) {
#pragma unroll 8
        for (int k = 0; k < 128; ++k) acc += m0[k] * Wl0[k * 64 + g];
    } else {
        const float* m = m1[c - 1];
#pragma unroll 8
        for (int k = 0; k < 192; ++k) acc += m[k] * Wl1[k * 64 + g];
    }
    o_lds[g * 4 + c] = acc * INV_AVG;
    __syncthreads();
    out[(size_t)n * 256 + t] = o_lds[t];
}

extern "C" void kernel_launch(void* const* d_in, const int* in_sizes, int n_in,
                              void* d_out, int out_size, void* d_ws, size_t ws_size,
                              hipStream_t stream) {
    const float* node_feats = (const float*)d_in[0];
    const float* edge_attrs = (const float*)d_in[1];
    const float* edge_feats = (const float*)d_in[2];
    const float* lengths    = (const float*)d_in[3];
    const int*   edge_index = (const int*)d_in[4];
    const float* Wsc   = (const float*)d_in[5];
    const float* Wup_s = (const float*)d_in[6];
    const float* Wup_v = (const float*)d_in[7];
    const float* W1 = (const float*)d_in[8];
    const float* b1 = (const float*)d_in[9];
    const float* W2 = (const float*)d_in[10];
    const float* b2 = (const float*)d_in[11];
    const float* W3 = (const float*)d_in[12];
    const float* Wl0 = (const float*)d_in[13];
    const float* Wl1 = (const float*)d_in[14];

    float* ws  = (float*)d_ws;
    float* NS  = ws;                            // N*64
    float* SUP = NS  + (size_t)N_NODES * 64;    // N*64
    float* VUP = SUP + (size_t)N_NODES * 64;    // N*192
    float* M0  = VUP + (size_t)N_NODES * 192;   // N*128
    float* M1  = M0  + (size_t)N_NODES * 128;   // N*576
    // Sort scratch: cnt/offs alias the (not-yet-zeroed) M0 region; perm lives
    // in d_out (dead until out_kernel overwrites it).
    int* cnt  = (int*)M0;                       // 8192 ints
    int* offs = cnt + N_NODES;                  // 8192 ints
    int* perm = (int*)d_out;                    // E ints (of 2M floats)

    // 1) build rcv-sorted permutation
    hipMemsetAsync(cnt, 0, N_NODES * sizeof(int), stream);
    hist_kernel<<<E_EDGES / 256, 256, 0, stream>>>(edge_index, cnt);
    scan_kernel<<<1, 256, 0, stream>>>(cnt, offs);
    perm_kernel<<<E_EDGES / 256, 256, 0, stream>>>(edge_index, offs, perm);

    // 2) zero accumulators (also wipes cnt/offs aliases)
    hipMemsetAsync(M0, 0, (size_t)N_NODES * (128 + 576) * sizeof(float), stream);

    // 3) main pipeline
    node_kernel<<<N_NODES, 64, 0, stream>>>(node_feats, Wsc, Wup_s, Wup_v, NS, SUP, VUP);
    edge_kernel<<<E_EDGES / (64 * WPB), 64 * WPB, 0, stream>>>(
        edge_attrs, edge_feats, lengths, edge_index, perm,
        W1, b1, W2, b2, W3, NS, SUP, VUP, M0, M1);
    out_kernel<<<N_NODES, 256, 0, stream>>>(M0, M1, Wl0, Wl1, (float*)d_out);
}

// Round 6
// 637.593 us; speedup vs baseline: 2.0162x; 1.8908x over previous
//
#include <hip/hip_runtime.h>

#define F 64
#define N_NODES 8192
#define E_EDGES 262144
#define EF 32
#define HID 64
#define INV_AVG (1.0f/32.0f)
#define INV_SQRT3 0.57735026918962576f
#define INV_SQRT2 0.70710678118654752f

__device__ __forceinline__ float silu(float x) {
    return x / (1.0f + __expf(-x));
}

// ---------------------------------------------------------------------------
// Sort prologue: counting sort of edges by rcv.
// ---------------------------------------------------------------------------
__global__ __launch_bounds__(256) void hist_kernel(
    const int* __restrict__ edge_index, int* __restrict__ cnt) {
    const int e = blockIdx.x * 256 + threadIdx.x;
    atomicAdd(&cnt[edge_index[E_EDGES + e]], 1);
}

__global__ __launch_bounds__(256) void scan_kernel(
    const int* __restrict__ cnt, int* __restrict__ offs) {
    __shared__ int part[256];
    const int t = threadIdx.x;
    int local[32];
    int s = 0;
#pragma unroll
    for (int i = 0; i < 32; ++i) { local[i] = s; s += cnt[t * 32 + i]; }
    part[t] = s;
    __syncthreads();
    for (int d = 1; d < 256; d <<= 1) {
        int v = (t >= d) ? part[t - d] : 0;
        __syncthreads();
        part[t] += v;
        __syncthreads();
    }
    const int prefix = (t == 0) ? 0 : part[t - 1];
#pragma unroll
    for (int i = 0; i < 32; ++i) offs[t * 32 + i] = prefix + local[i];
}

__global__ __launch_bounds__(256) void perm_kernel(
    const int* __restrict__ edge_index, int* __restrict__ offs,
    int* __restrict__ perm) {
    const int e = blockIdx.x * 256 + threadIdx.x;
    const int pos = atomicAdd(&offs[edge_index[E_EDGES + e]], 1);
    perm[pos] = e;
}

// ---------------------------------------------------------------------------
// Kernel: node transforms.  NS = s@Wsc, SUP = s@Wup_s, VUP[n][c][g] = v@Wup_v
// ---------------------------------------------------------------------------
__global__ __launch_bounds__(64) void node_kernel(
    const float* __restrict__ node_feats,
    const float* __restrict__ Wsc,
    const float* __restrict__ Wup_s,
    const float* __restrict__ Wup_v,
    float* __restrict__ NS,
    float* __restrict__ SUP,
    float* __restrict__ VUP) {
    const int n = blockIdx.x;
    const int g = threadIdx.x;
    __shared__ float s_lds[64];
    __shared__ float v_lds[3][64];

    const float* nf = node_feats + (size_t)n * 256;
    s_lds[g] = nf[g];
    v_lds[0][g] = nf[64 + g * 3 + 0];
    v_lds[1][g] = nf[64 + g * 3 + 1];
    v_lds[2][g] = nf[64 + g * 3 + 2];
    __syncthreads();

    float ns = 0.f, su = 0.f, vu0 = 0.f, vu1 = 0.f, vu2 = 0.f;
#pragma unroll 8
    for (int k = 0; k < 64; ++k) {
        const float sk = s_lds[k];
        ns += sk * Wsc[k * 64 + g];
        su += sk * Wup_s[k * 64 + g];
        const float w = Wup_v[k * 64 + g];
        vu0 += v_lds[0][k] * w;
        vu1 += v_lds[1][k] * w;
        vu2 += v_lds[2][k] * w;
    }
    NS[n * 64 + g] = ns;
    SUP[n * 64 + g] = su;
    VUP[(n * 3 + 0) * 64 + g] = vu0;
    VUP[(n * 3 + 1) * 64 + g] = vu1;
    VUP[(n * 3 + 2) * 64 + g] = vu2;
}

// ---------------------------------------------------------------------------
// Fused edge kernel: ONE wave per block (64 edges), lane = edge, rcv-sorted.
// Single-wave workgroup: __syncthreads() at cross-lane LDS hand-offs compiles
// to just a waitcnt fence (backend drops s_barrier for 1-wave groups) — free
// safety. Gather loops use explicit 4-wide register batching; weight k-loops
// unroll-2 to double s_load bytes per wait point.
// ---------------------------------------------------------------------------
#define BATCH 4
__global__ __launch_bounds__(64, 4) void edge_kernel(
    const float* __restrict__ edge_attrs,
    const float* __restrict__ edge_feats,
    const float* __restrict__ lengths,
    const int*   __restrict__ edge_index,
    const int*   __restrict__ perm,
    const float* __restrict__ W1, const float* __restrict__ b1,
    const float* __restrict__ W2, const float* __restrict__ b2,
    const float* __restrict__ W3,
    const float* __restrict__ NS,
    const float* __restrict__ SUP,
    const float* __restrict__ VUP,
    float* __restrict__ M0,
    float* __restrict__ M1) {
    const int lane = threadIdx.x;        // 0..63
    const int e0   = blockIdx.x * 64;

    __shared__ float xt[64][33];         // staging / transpose / h2-stash
    __shared__ int   snd_s[64];
    __shared__ int   rcv_s[64];
    __shared__ int   pe_s[64];
    __shared__ float attr_s[4][64];

    // ---- edge metadata (sorted order) ----
    const int pe  = perm[e0 + lane];
    const int snd = edge_index[pe];
    const int rcv = edge_index[E_EDGES + pe];
    const float len = lengths[pe];
    const float4 a4 = ((const float4*)edge_attrs)[pe];
    snd_s[lane] = snd;
    rcv_s[lane] = rcv;
    pe_s[lane]  = pe;
    attr_s[0][lane] = a4.x;
    attr_s[1][lane] = a4.y;
    attr_s[2][lane] = a4.z;
    attr_s[3][lane] = a4.w;
    __syncthreads();

    const int kk0 = lane & 31;
    const int jh  = lane >> 5;

    // ---- layer 1: 161 -> 64, acc[g] in VGPRs ----
    float acc[64];
#pragma unroll
    for (int g = 0; g < 64; ++g) acc[g] = b1[g];

#pragma unroll
    for (int t = 0; t < 5; ++t) {
        // stage 64 edges x 32 features, 4-wide load batching
        for (int i0 = 0; i0 < 32; i0 += BATCH) {
            float tmp[BATCH];
#pragma unroll
            for (int u = 0; u < BATCH; ++u) {
                const int j = 2 * (i0 + u) + jh;
                if (t < 4) {
                    const int node = (t < 2) ? snd_s[j] : rcv_s[j];
                    tmp[u] = NS[node * 64 + (t & 1) * 32 + kk0];
                } else {
                    tmp[u] = edge_feats[(size_t)pe_s[j] * EF + kk0];
                }
            }
#pragma unroll
            for (int u = 0; u < BATCH; ++u) xt[2 * (i0 + u) + jh][kk0] = tmp[u];
        }
        __syncthreads();
#pragma unroll 2
        for (int kk = 0; kk < 32; ++kk) {
            const float x = xt[lane][kk];
            const float* wr = W1 + (t * 32 + kk) * 64;
#pragma unroll
            for (int g = 0; g < 64; ++g) acc[g] += x * wr[g];
        }
        __syncthreads();
    }
    {   // k = 160: length (lane-local)
        const float* wr = W1 + 160 * 64;
#pragma unroll
        for (int g = 0; g < 64; ++g) acc[g] += len * wr[g];
    }
#pragma unroll
    for (int k = 0; k < 64; ++k) acc[k] = silu(acc[k]);   // h1 in regs

    // ---- layer 2: 64 -> 64 in two 32-chunks (lane-local LDS stash) ----
    for (int ch = 0; ch < 2; ++ch) {
        const int gbase = (ch == 0) ? 32 : 0;
        const float* W2b = W2 + gbase;
        float acc2[32];
#pragma unroll
        for (int gg = 0; gg < 32; ++gg) acc2[gg] = b2[gbase + gg];
#pragma unroll 2
        for (int k = 0; k < 64; ++k) {
            const float hk = acc[k];
#pragma unroll
            for (int gg = 0; gg < 32; ++gg) acc2[gg] += hk * W2b[k * 64 + gg];
        }
        if (ch == 0) {
#pragma unroll
            for (int gg = 0; gg < 32; ++gg) xt[lane][gg] = silu(acc2[gg]);
        } else {
#pragma unroll
            for (int gg = 0; gg < 32; ++gg) acc[gg] = silu(acc2[gg]);
#pragma unroll
            for (int gg = 0; gg < 32; ++gg) acc[32 + gg] = xt[lane][gg];
        }
    }
    // acc[] now holds h2.

    // ---- layer 3 (ten 32-wide chunks) + transpose + run-aggregated scatter
    const int halfsel = lane >> 5;
    const int gl      = lane & 31;

    for (int c = 0; c < 5; ++c) {
        for (int hh = 0; hh < 2; ++hh) {
            const float* W3b = W3 + c * 64 + hh * 32;
            float acc3[32];
#pragma unroll
            for (int gg = 0; gg < 32; ++gg) acc3[gg] = 0.f;
#pragma unroll 2
            for (int k = 0; k < 64; ++k) {
                const float hk = acc[k];
#pragma unroll
                for (int gg = 0; gg < 32; ++gg) acc3[gg] += hk * W3b[k * 320 + gg];
            }
            // transpose to lane=feature (fence before overwriting prev chunk,
            // fence after writes before cross-lane reads)
            __syncthreads();
#pragma unroll
            for (int gg = 0; gg < 32; ++gg) xt[lane][gg] = acc3[gg];
            __syncthreads();

            const int g = hh * 32 + gl;
            int   cur = -1;
            float r0 = 0.f, r1 = 0.f, r2 = 0.f;
            for (int u0 = 0; u0 < 32; u0 += BATCH) {
                // batched gather phase
                float ld0[BATCH], ld1[BATCH], ld2[BATCH];
#pragma unroll
                for (int u = 0; u < BATCH; ++u) {
                    const int j = 32 * halfsel + u0 + u;
                    const int sndj = snd_s[j];
                    if (c == 0 || c == 2) {
                        ld0[u] = SUP[sndj * 64 + g];
                    } else {
                        ld0[u] = VUP[(sndj * 3 + 0) * 64 + g];
                        ld1[u] = VUP[(sndj * 3 + 1) * 64 + g];
                        ld2[u] = VUP[(sndj * 3 + 2) * 64 + g];
                    }
                }
                // compute phase
#pragma unroll
                for (int u = 0; u < BATCH; ++u) {
                    const int j = 32 * halfsel + u0 + u;
                    const int rcvj = rcv_s[j];
                    if (rcvj != cur) {
                        if (cur >= 0) {
                            if (c == 0)      atomicAdd(&M0[(size_t)cur * 128 + g], r0);
                            else if (c == 1) atomicAdd(&M0[(size_t)cur * 128 + 64 + g], r0);
                            else {
                                float* M1r = M1 + (size_t)cur * 576;
                                const int off = (c == 2) ? 0 : (c == 3) ? 64 : 128;
                                atomicAdd(M1r + off + g, r0);
                                atomicAdd(M1r + 192 + off + g, r1);
                                atomicAdd(M1r + 384 + off + g, r2);
                            }
                        }
                        cur = rcvj; r0 = r1 = r2 = 0.f;
                    }
                    const float tv = xt[j][gl];
                    if (c == 0) {
                        r0 += ld0[u] * attr_s[0][j] * tv;
                    } else if (c == 1) {
                        r0 += (ld0[u] * attr_s[1][j] + ld1[u] * attr_s[2][j]
                               + ld2[u] * attr_s[3][j]) * (INV_SQRT3 * tv);
                    } else if (c == 2) {
                        const float sstv = ld0[u] * tv;
                        r0 += sstv * attr_s[1][j];
                        r1 += sstv * attr_s[2][j];
                        r2 += sstv * attr_s[3][j];
                    } else if (c == 3) {
                        const float a0tv = attr_s[0][j] * tv;
                        r0 += ld0[u] * a0tv;
                        r1 += ld1[u] * a0tv;
                        r2 += ld2[u] * a0tv;
                    } else {
                        const float a1j = attr_s[1][j];
                        const float a2j = attr_s[2][j];
                        const float a3j = attr_s[3][j];
                        const float s2t = INV_SQRT2 * tv;
                        r0 += (ld1[u] * a3j - ld2[u] * a2j) * s2t;
                        r1 += (ld2[u] * a1j - ld0[u] * a3j) * s2t;
                        r2 += (ld0[u] * a2j - ld1[u] * a1j) * s2t;
                    }
                }
            }
            // final flush
            if (cur >= 0) {
                if (c == 0)      atomicAdd(&M0[(size_t)cur * 128 + g], r0);
                else if (c == 1) atomicAdd(&M0[(size_t)cur * 128 + 64 + g], r0);
                else {
                    float* M1r = M1 + (size_t)cur * 576;
                    const int off = (c == 2) ? 0 : (c == 3) ? 64 : 128;
                    atomicAdd(M1r + off + g, r0);
                    atomicAdd(M1r + 192 + off + g, r1);
                    atomicAdd(M1r + 384 + off + g, r2);
                }
            }
        }
    }
}

// ---------------------------------------------------------------------------
// Kernel: per-node output projections.
// ---------------------------------------------------------------------------
__global__ __launch_bounds__(256) void out_kernel(
    const float* __restrict__ M0,
    const float* __restrict__ M1,
    const float* __restrict__ Wl0,
    const float* __restrict__ Wl1,
    float* __restrict__ out) {
    const int n = blockIdx.x;
    const int t = threadIdx.x;
    __shared__ float m0[128];
    __shared__ float m1[3][192];
    __shared__ float o_lds[256];

    if (t < 128) m0[t] = M0[(size_t)n * 128 + t];
    for (int i = t; i < 576; i += 256) m1[i / 192][i % 192] = M1[(size_t)n * 576 + i];
    __syncthreads();

    const int c = t >> 6;
    const int g = t & 63;
    float acc = 0.f;
    if (c == 0) {
#pragma unroll 8
        for (int k = 0; k < 128; ++k) acc += m0[k] * Wl0[k * 64 + g];
    } else {
        const float* m = m1[c - 1];
#pragma unroll 8
        for (int k = 0; k < 192; ++k) acc += m[k] * Wl1[k * 64 + g];
    }
    o_lds[g * 4 + c] = acc * INV_AVG;
    __syncthreads();
    out[(size_t)n * 256 + t] = o_lds[t];
}

extern "C" void kernel_launch(void* const* d_in, const int* in_sizes, int n_in,
                              void* d_out, int out_size, void* d_ws, size_t ws_size,
                              hipStream_t stream) {
    const float* node_feats = (const float*)d_in[0];
    const float* edge_attrs = (const float*)d_in[1];
    const float* edge_feats = (const float*)d_in[2];
    const float* lengths    = (const float*)d_in[3];
    const int*   edge_index = (const int*)d_in[4];
    const float* Wsc   = (const float*)d_in[5];
    const float* Wup_s = (const float*)d_in[6];
    const float* Wup_v = (const float*)d_in[7];
    const float* W1 = (const float*)d_in[8];
    const float* b1 = (const float*)d_in[9];
    const float* W2 = (const float*)d_in[10];
    const float* b2 = (const float*)d_in[11];
    const float* W3 = (const float*)d_in[12];
    const float* Wl0 = (const float*)d_in[13];
    const float* Wl1 = (const float*)d_in[14];

    float* ws  = (float*)d_ws;
    float* NS  = ws;                            // N*64
    float* SUP = NS  + (size_t)N_NODES * 64;    // N*64
    float* VUP = SUP + (size_t)N_NODES * 64;    // N*192
    float* M0  = VUP + (size_t)N_NODES * 192;   // N*128
    float* M1  = M0  + (size_t)N_NODES * 128;   // N*576
    int* cnt  = (int*)M0;                       // aliases M0 (wiped later)
    int* offs = cnt + N_NODES;
    int* perm = (int*)d_out;                    // dead until out_kernel

    // 1) build rcv-sorted permutation
    hipMemsetAsync(cnt, 0, N_NODES * sizeof(int), stream);
    hist_kernel<<<E_EDGES / 256, 256, 0, stream>>>(edge_index, cnt);
    scan_kernel<<<1, 256, 0, stream>>>(cnt, offs);
    perm_kernel<<<E_EDGES / 256, 256, 0, stream>>>(edge_index, offs, perm);

    // 2) zero accumulators (also wipes cnt/offs aliases)
    hipMemsetAsync(M0, 0, (size_t)N_NODES * (128 + 576) * sizeof(float), stream);

    // 3) main pipeline
    node_kernel<<<N_NODES, 64, 0, stream>>>(node_feats, Wsc, Wup_s, Wup_v, NS, SUP, VUP);
    edge_kernel<<<E_EDGES / 64, 64, 0, stream>>>(
        edge_attrs, edge_feats, lengths, edge_index, perm,
        W1, b1, W2, b2, W3, NS, SUP, VUP, M0, M1);
    out_kernel<<<N_NODES, 256, 0, stream>>>(M0, M1, Wl0, Wl1, (float*)d_out);
}